// Round 3
// baseline (9.739 us; speedup 1.0000x reference)
//
#include <hip/hip_runtime.h>
#include <math.h>

#define BOHR_D 0.52917721092

// DPP lane-permute at VALU rate (quad_perm / row ops within 16-lane rows).
template<int CTRL>
__device__ __forceinline__ float fdpp(float x) {
    return __builtin_bit_cast(float,
        __builtin_amdgcn_update_dpp(0, __builtin_bit_cast(int, x), CTRL, 0xF, 0xF, true));
}

__global__ __launch_bounds__(256) void angsym_kernel(
    const float* __restrict__ d_cutoff,   // (B,N,N)
    const float* __restrict__ d,          // (B,N,N)
    const float* __restrict__ coords,     // (B,N,3)
    float* __restrict__ out)              // (B,N,40)
{
    __shared__ __align__(16) float cxyz[96];
    __shared__ __align__(16) float drow[32];
    __shared__ __align__(16) float frow[32];
    __shared__ float red[4 * 40];

    const int bi  = blockIdx.x;           // b*32 + i
    const int b   = bi >> 5;
    const int i   = bi & 31;
    const int tid = threadIdx.x;

    // Stage coords (24 float4) and the i-th rows of d / d_cutoff (8 float4 each).
    if (tid < 24)
        ((float4*)cxyz)[tid] = ((const float4*)(coords + b * 96))[tid];
    else if (tid >= 64 && tid < 72)
        ((float4*)drow)[tid - 64] = ((const float4*)(d + (b * 32 + i) * 32))[tid - 64];
    else if (tid >= 72 && tid < 80)
        ((float4*)frow)[tid - 72] = ((const float4*)(d_cutoff + (b * 32 + i) * 32))[tid - 72];
    __syncthreads();

    const float cix = cxyz[3 * i], ciy = cxyz[3 * i + 1], ciz = cxyz[3 * i + 2];

    // cos/sin of the f32 theta offsets {1.57f, 3.14f, 4.71f}
    const float C1 = (float)0.00079632671073326442;
    const float S1 = (float)0.99999968293183461;
    const float C2 = (float)-0.99999873172753954;
    const float S2 = (float)0.0015926529164868282;
    const float C3 = (float)-0.0023889083720362966;
    const float S3 = (float)-0.99999714638771537;

    const float RS[5] = {
        (float)(0.5  / BOHR_D),
        (float)(1.17 / BOHR_D),
        (float)(1.83 / BOHR_D),
        (float)(2.5  / BOHR_D),
        (float)(3.17 / BOHR_D)
    };
    const float KE = -1.6158184504300992f;   // -1.12 * log2(e)

    float a[40];
    #pragma unroll
    for (int p = 0; p < 40; ++p) a[p] = 0.f;

    // One (j<=k) pair of the 528; off-diagonal weighted x2.
    auto pair = [&](int m) {
        // triangular decode; exact at boundaries (perfect-square discriminant,
        // correctly-rounded sqrtf).
        const float disc = sqrtf(4225.0f - 8.0f * (float)m);
        const int j = (int)((65.0f - disc) * 0.5f);
        const int k = j + m - ((j * (65 - j)) >> 1);

        const float vjx = cix - cxyz[3 * j];
        const float vjy = ciy - cxyz[3 * j + 1];
        const float vjz = ciz - cxyz[3 * j + 2];
        const float vkx = cix - cxyz[3 * k];
        const float vky = ciy - cxyz[3 * k + 1];
        const float vkz = ciz - cxyz[3 * k + 2];

        const float dot = vjx * vkx + vjy * vky + vjz * vkz;
        const float Rij = drow[j];
        const float Rik = drow[k];
        const float theta = dot / (Rij * Rik + 1e-5f);   // IEEE div (ref-match)
        float cut = frow[j] * frow[k];
        cut = (j != k) ? cut * 2.0f : cut;
        const float avg = (Rij + Rik) * 0.5f;

        // f64 range reduction, then HW sin/cos (arg in revolutions)
        double td = (double)theta * 0.15915494309189535;
        td -= floor(td);
        const float rev = (float)td;
        const float s = __builtin_amdgcn_sinf(rev);
        const float c = __builtin_amdgcn_cosf(rev);

        const float cts[4] = { c,
                               c * C1 + s * S1,
                               c * C2 + s * S2,
                               c * C3 + s * S3 };
        float angp[4], angm[4];
        #pragma unroll
        for (int t = 0; t < 4; ++t) {
            const float ap  = 1.f + cts[t];
            const float am  = 1.f - cts[t];
            const float ap2 = ap * ap;
            const float am2 = am * am;
            angp[t] = ap2 * ap2;
            angm[t] = am2 * am2;
        }

        #pragma unroll
        for (int r = 0; r < 5; ++r) {
            const float dd = avg - RS[r];
            const float w  = cut * __builtin_amdgcn_exp2f(KE * dd * dd);
            #pragma unroll
            for (int t = 0; t < 4; ++t) {
                a[r * 4 + t]      += w * angp[t];   // lambda = +1
                a[20 + r * 4 + t] += w * angm[t];   // lambda = -1
            }
        }
    };

    pair(tid);
    pair(tid + 256);
    if (tid < 16) pair(tid + 512);   // divergent tail: only wave 0 pays

    // Split-butterfly reduce. Split levels use DPP (VALU rate) on lane bits
    // {0:xor1, 1:xor2, 3:xor8}; plain sums over bits {2:xor4, 4:xor16, 5:xor32}.
    const int lane = tid & 63;
    const int wave = tid >> 6;
    const bool s0 = (lane & 1) != 0;
    const bool s1 = (lane & 2) != 0;
    const bool s3 = (lane & 8) != 0;

    #pragma unroll
    for (int m_ = 0; m_ < 20; ++m_) {           // xor1: quad_perm [1,0,3,2]
        const float plo = a[m_]      + fdpp<0xB1>(a[m_]);
        const float phi = a[m_ + 20] + fdpp<0xB1>(a[m_ + 20]);
        a[m_] = s0 ? phi : plo;
    }
    #pragma unroll
    for (int m_ = 0; m_ < 10; ++m_) {           // xor2: quad_perm [2,3,0,1]
        const float plo = a[m_]      + fdpp<0x4E>(a[m_]);
        const float phi = a[m_ + 10] + fdpp<0x4E>(a[m_ + 10]);
        a[m_] = s1 ? phi : plo;
    }
    #pragma unroll
    for (int m_ = 0; m_ < 5; ++m_) {            // xor8: row_ror:8 (involution)
        const float plo = a[m_]     + fdpp<0x128>(a[m_]);
        const float phi = a[m_ + 5] + fdpp<0x128>(a[m_ + 5]);
        a[m_] = s3 ? phi : plo;
    }
    #pragma unroll
    for (int m_ = 0; m_ < 5; ++m_) {            // plain sums over bits 2,4,5
        a[m_] += __shfl_xor(a[m_], 4);
        a[m_] += __shfl_xor(a[m_], 16);
        a[m_] += __shfl_xor(a[m_], 32);
    }

    const int base5 = (s0 ? 4 : 0) + (s1 ? 2 : 0) + (s3 ? 1 : 0);
    if ((lane & 52) == 0) {                     // bits 2,4,5 clear -> writer
        #pragma unroll
        for (int q = 0; q < 5; ++q)
            red[wave * 40 + base5 * 5 + q] = a[q];
    }
    __syncthreads();

    if (tid < 40) {
        const float v = red[tid] + red[40 + tid] + red[80 + tid] + red[120 + tid];
        out[bi * 40 + tid] = v * 0.125f;        // 2^(1-zeta)
    }
}

extern "C" void kernel_launch(void* const* d_in, const int* in_sizes, int n_in,
                              void* d_out, int out_size, void* d_ws, size_t ws_size,
                              hipStream_t stream) {
    const float* d_cutoff = (const float*)d_in[0];
    const float* d        = (const float*)d_in[1];
    const float* coords   = (const float*)d_in[2];
    float* out            = (float*)d_out;

    angsym_kernel<<<512, 256, 0, stream>>>(d_cutoff, d, coords, out);
}